// Round 9
// baseline (294.682 us; speedup 1.0000x reference)
//
#include <hip/hip_runtime.h>

#define D 64
#define BLK 256

#define NBSHIFT 9
#define NODES_PER_BKT 512              // bucket = row >> 9; NB <= 256 for N <= 131072
#define TA 4096                        // edges per binA tile
#define CVT_BLOCKS 512                 // grid-strided cvt

typedef unsigned int uint32;
typedef __attribute__((ext_vector_type(8))) short bf16x8;
typedef __attribute__((ext_vector_type(4))) float f32x4;

// ---- bf16 helpers (RTNE) ----
__device__ inline uint32 f2bf_u(float f) {
    uint32 u = __float_as_uint(f);
    u += 0x7FFFu + ((u >> 16) & 1u);
    return u >> 16;
}

// ---------------- fused pre-pass: cvt (grid-stride x->bf16) + wf (W repack) + hist ----------------
__global__ void pre_kernel(const float* __restrict__ x, uint2* __restrict__ xb, int n4,
                           const float* __restrict__ W, uint4* __restrict__ Wf,
                           const int* __restrict__ row, uint32* __restrict__ bcount, int E) {
    int bid = blockIdx.x;
    if (bid < CVT_BLOCKS) {
        int stride = CVT_BLOCKS * BLK;
        for (int i = bid * BLK + threadIdx.x; i < n4; i += stride) {
            float4 v = ((const float4*)x)[i];
            uint2 pack;
            pack.x = f2bf_u(v.x) | (f2bf_u(v.y) << 16);
            pack.y = f2bf_u(v.z) | (f2bf_u(v.w) << 16);
            xb[i] = pack;
        }
        return;
    }
    if (bid < CVT_BLOCKS + 8) {
        int tid = (bid - CVT_BLOCKS) * 256 + threadIdx.x;   // 0..2047
        int l = tid & 63;
        int g = tid >> 6;       // 0..31
        int kh = g & 1;
        int t = (g >> 1) & 3;
        int w = g >> 3;
        int n = t * 16 + (l & 15);
        int kbase = kh * 32 + (l >> 4) * 8;
        uint32 pk[4];
        #pragma unroll
        for (int i = 0; i < 4; ++i) {
            uint32 b0 = f2bf_u(W[(size_t)w * 4096 + (size_t)(kbase + 2 * i) * 64 + n]);
            uint32 b1 = f2bf_u(W[(size_t)w * 4096 + (size_t)(kbase + 2 * i + 1) * 64 + n]);
            pk[i] = b0 | (b1 << 16);
        }
        Wf[tid] = make_uint4(pk[0], pk[1], pk[2], pk[3]);
        return;
    }
    // hist
    __shared__ uint32 h[256];
    int tid = threadIdx.x;
    h[tid] = 0;
    __syncthreads();
    int base = (bid - CVT_BLOCKS - 8) * TA;
    int end = min(base + TA, E);
    for (int e = base + tid; e < end; e += 256)
        atomicAdd(&h[(uint32)row[e] >> NBSHIFT], 1u);
    __syncthreads();
    if (h[tid]) atomicAdd(&bcount[tid], h[tid]);
}

// ---------------- pass A: bin (rowlocal<<17|col, attr) by bucket ----------------
__global__ void binA_kernel(const int* __restrict__ row, const int* __restrict__ col,
                            const float* __restrict__ attr, const uint32* __restrict__ bcount,
                            uint32* __restrict__ gcursor, int2* __restrict__ binned, int E) {
    __shared__ uint32 hist[256], baseg[256], lstart[256], lcur[256];
    __shared__ int2 stage[TA];
    __shared__ unsigned char sbkt[TA];
    int tid = threadIdx.x;
    int tile = blockIdx.x * TA;
    hist[tid] = 0;
    __syncthreads();

    uint32 px[16], py[16], bk[16];
    #pragma unroll
    for (int k = 0; k < 16; ++k) {
        int e = tile + k * 256 + tid;
        bk[k] = 0xFFFFFFFFu;
        if (e < E) {
            int r = row[e], c = col[e];
            uint32 b = (uint32)r >> NBSHIFT;
            bk[k] = b;
            px[k] = ((uint32)(r & (NODES_PER_BKT - 1)) << 17) | (uint32)c;
            py[k] = __float_as_uint(attr[e]);
            atomicAdd(&hist[b], 1u);
        }
    }
    __syncthreads();
    // local scan of bcount -> global bucket bases
    uint32 bc = bcount[tid];
    lcur[tid] = bc;
    __syncthreads();
    for (int off = 1; off < 256; off <<= 1) {
        uint32 t = (tid >= off) ? lcur[tid - off] : 0u;
        __syncthreads();
        lcur[tid] += t;
        __syncthreads();
    }
    uint32 gexcl = lcur[tid] - bc;
    if (hist[tid] > 0) baseg[tid] = gexcl + atomicAdd(&gcursor[tid], hist[tid]);
    __syncthreads();
    // local scan of this tile's histogram
    lcur[tid] = hist[tid];
    __syncthreads();
    for (int off = 1; off < 256; off <<= 1) {
        uint32 t = (tid >= off) ? lcur[tid - off] : 0u;
        __syncthreads();
        lcur[tid] += t;
        __syncthreads();
    }
    lstart[tid] = lcur[tid] - hist[tid];
    lcur[tid] = lstart[tid];
    __syncthreads();
    #pragma unroll
    for (int k = 0; k < 16; ++k) {
        if (bk[k] != 0xFFFFFFFFu) {
            uint32 pos = atomicAdd(&lcur[bk[k]], 1u);
            stage[pos] = make_int2((int)px[k], (int)py[k]);
            sbkt[pos] = (unsigned char)bk[k];
        }
    }
    __syncthreads();
    int cnt = min(TA, E - tile);
    for (int i = tid; i < cnt; i += 256) {
        uint32 b = sbkt[i];
        uint32 dst = baseg[b] + (uint32)i - lstart[b];
        binned[dst] = stage[i];
    }
}

// ---------------- pass B1: per-bucket degree count in LDS -> rowptr + dinv ----------------
__global__ void binBdeg_kernel(const int2* __restrict__ binned, const uint32* __restrict__ bcount,
                               uint32* __restrict__ rowptr, float* __restrict__ dinv,
                               int N, int E) {
    __shared__ uint32 cnt[NODES_PER_BKT];
    __shared__ uint32 ps[256];
    int b = blockIdx.x;
    int tid = threadIdx.x;
    cnt[tid] = 0;
    cnt[tid + 256] = 0;
    // local inclusive scan of bcount -> bucket [start,end)
    uint32 bc = bcount[tid];
    ps[tid] = bc;
    __syncthreads();
    for (int off = 1; off < 256; off <<= 1) {
        uint32 t = (tid >= off) ? ps[tid - off] : 0u;
        __syncthreads();
        ps[tid] += t;
        __syncthreads();
    }
    uint32 incl_b = ps[b];
    uint32 bc_b = bcount[b];
    uint32 start = incl_b - bc_b, end = incl_b;
    __syncthreads();                      // done with ps as bucket scan
    for (uint32 i = start + tid; i < end; i += 256)
        atomicAdd(&cnt[(uint32)binned[i].x >> 17], 1u);
    __syncthreads();
    uint32 c0 = cnt[2 * tid], c1 = cnt[2 * tid + 1];
    ps[tid] = c0 + c1;
    __syncthreads();
    for (int off = 1; off < 256; off <<= 1) {
        uint32 t = (tid >= off) ? ps[tid - off] : 0u;
        __syncthreads();
        ps[tid] += t;
        __syncthreads();
    }
    uint32 pexcl = ps[tid] - (c0 + c1);
    int base = b << NBSHIFT;
    int n0 = base + 2 * tid, n1 = n0 + 1;
    if (n0 < N) {
        rowptr[n0] = start + pexcl;
        dinv[n0] = c0 ? rsqrtf((float)c0) : 0.0f;
    }
    if (n1 < N) {
        rowptr[n1] = start + pexcl + c0;
        dinv[n1] = c1 ? rsqrtf((float)c1) : 0.0f;
    }
    if (b == (int)gridDim.x - 1 && tid == 0) rowptr[N] = (uint32)E;
}

// ---------------- pass B2: per-bucket sort + lap; pairs.x = col<<7 (byte offset) ----------------
__global__ void binBsort_kernel(const int2* __restrict__ binned, const uint32* __restrict__ bcount,
                                const uint32* __restrict__ rowptr, const float* __restrict__ dinv,
                                int2* __restrict__ pairs, int N) {
    __shared__ uint32 lcur[NODES_PER_BKT];
    __shared__ float ldin[NODES_PER_BKT];
    __shared__ uint32 ps[256];
    int b = blockIdx.x;
    int tid = threadIdx.x;
    int base = b << NBSHIFT;
    // local inclusive scan of bcount -> bucket [start,end)
    uint32 bc = bcount[tid];
    ps[tid] = bc;
    __syncthreads();
    for (int off = 1; off < 256; off <<= 1) {
        uint32 t = (tid >= off) ? ps[tid - off] : 0u;
        __syncthreads();
        ps[tid] += t;
        __syncthreads();
    }
    uint32 incl_b = ps[b];
    uint32 start = incl_b - bcount[b], end = incl_b;
    for (int t = tid; t < NODES_PER_BKT; t += 256) {
        int node = base + t;
        lcur[t] = (node < N) ? (rowptr[node] - start) : 0u;
        ldin[t] = (node < N) ? dinv[node] : 0.0f;
    }
    __syncthreads();
    for (uint32 i = start + tid; i < end; i += 256) {
        int2 rec = binned[i];
        uint32 x = (uint32)rec.x;
        uint32 rl = x >> 17;
        uint32 c = x & 0x1FFFFu;
        float lap = -ldin[rl] * __int_as_float(rec.y) * dinv[c];
        uint32 pos = atomicAdd(&lcur[rl], 1u);
        pairs[start + pos] = make_int2((int)(c << 7), __float_as_int(lap));
    }
}

// ---------------- CSR SpMM burst macros (v7, measured best) ----------------
#define LOAD16(J, END, ESAFE, M0, M1, H0, H1)                          \
    {                                                                  \
        uint32 i0_ = (J) + q, i1_ = (J) + 8 + q;                       \
        uint32 c0_ = (i0_ < (END)) ? i0_ : (ESAFE);                    \
        uint32 c1_ = (i1_ < (END)) ? i1_ : (ESAFE);                    \
        M0 = pairs[c0_];                                               \
        M1 = pairs[c1_];                                               \
        H0 = *(const uint4*)(hb + (uint32)M0.x + off);                 \
        H1 = *(const uint4*)(hb + (uint32)M1.x + off);                 \
    }

#define FMA16(J, END, M0, M1, H0, H1, A)                               \
    {                                                                  \
        uint32 i0_ = (J) + q, i1_ = (J) + 8 + q;                       \
        float l0_ = (i0_ < (END)) ? __int_as_float(M0.y) : 0.0f;       \
        float l1_ = (i1_ < (END)) ? __int_as_float(M1.y) : 0.0f;       \
        A[0] += l0_ * __uint_as_float(H0.x << 16);                     \
        A[1] += l0_ * __uint_as_float(H0.x & 0xFFFF0000u);             \
        A[2] += l0_ * __uint_as_float(H0.y << 16);                     \
        A[3] += l0_ * __uint_as_float(H0.y & 0xFFFF0000u);             \
        A[4] += l0_ * __uint_as_float(H0.z << 16);                     \
        A[5] += l0_ * __uint_as_float(H0.z & 0xFFFF0000u);             \
        A[6] += l0_ * __uint_as_float(H0.w << 16);                     \
        A[7] += l0_ * __uint_as_float(H0.w & 0xFFFF0000u);             \
        A[0] += l1_ * __uint_as_float(H1.x << 16);                     \
        A[1] += l1_ * __uint_as_float(H1.x & 0xFFFF0000u);             \
        A[2] += l1_ * __uint_as_float(H1.y << 16);                     \
        A[3] += l1_ * __uint_as_float(H1.y & 0xFFFF0000u);             \
        A[4] += l1_ * __uint_as_float(H1.z << 16);                     \
        A[5] += l1_ * __uint_as_float(H1.z & 0xFFFF0000u);             \
        A[6] += l1_ * __uint_as_float(H1.w << 16);                     \
        A[7] += l1_ * __uint_as_float(H1.w & 0xFFFF0000u);             \
    }

// 2-row spmm burst: computes r[8] for rows nA, nA+1 on lane groups q=0/1; others contribute partials.
#define SPMM_BURST(NA, AA, AB)                                                        \
    {                                                                                 \
        bool hasB_ = ((NA) + 1 < N);                                                  \
        uint2 rpA_ = *(const uint2*)(rowptr + (NA));                                  \
        uint32 eBr_ = hasB_ ? rowptr[(NA) + 2] : rpA_.y;                              \
        uint32 jA = __builtin_amdgcn_readfirstlane(rpA_.x);                           \
        uint32 endA = __builtin_amdgcn_readfirstlane(rpA_.y);                         \
        uint32 jB = endA;                                                             \
        uint32 endB = __builtin_amdgcn_readfirstlane(eBr_);                           \
        uint32 esA = (endA > jA) ? endA - 1 : 0u;                                     \
        uint32 esB = (endB > jB) ? endB - 1 : 0u;                                     \
        int2 mA0, mA1, mA2, mA3, mB0, mB1, mB2, mB3;                                  \
        uint4 hA0, hA1, hA2, hA3, hB0, hB1, hB2, hB3;                                 \
        bool dA = (jA + 16 < endA);                                                   \
        bool dB = (jB + 16 < endB);                                                   \
        LOAD16(jA, endA, esA, mA0, mA1, hA0, hA1);                                    \
        LOAD16(jB, endB, esB, mB0, mB1, hB0, hB1);                                    \
        if (dA) LOAD16(jA + 16, endA, esA, mA2, mA3, hA2, hA3);                       \
        if (dB) LOAD16(jB + 16, endB, esB, mB2, mB3, hB2, hB3);                       \
        FMA16(jA, endA, mA0, mA1, hA0, hA1, AA);                                      \
        FMA16(jB, endB, mB0, mB1, hB0, hB1, AB);                                      \
        if (dA) FMA16(jA + 16, endA, mA2, mA3, hA2, hA3, AA);                         \
        if (dB) FMA16(jB + 16, endB, mB2, mB3, hB2, hB3, AB);                         \
        jA += 32;                                                                     \
        jB += 32;                                                                     \
        while (jA < endA) {                                                           \
            LOAD16(jA, endA, esA, mA0, mA1, hA0, hA1);                                \
            FMA16(jA, endA, mA0, mA1, hA0, hA1, AA);                                  \
            if (jA + 16 < endA) {                                                     \
                LOAD16(jA + 16, endA, esA, mA2, mA3, hA2, hA3);                       \
                FMA16(jA + 16, endA, mA2, mA3, hA2, hA3, AA);                         \
            }                                                                         \
            jA += 32;                                                                 \
        }                                                                             \
        while (jB < endB) {                                                           \
            LOAD16(jB, endB, esB, mB0, mB1, hB0, hB1);                                \
            FMA16(jB, endB, mB0, mB1, hB0, hB1, AB);                                  \
            if (jB + 16 < endB) {                                                     \
                LOAD16(jB + 16, endB, esB, mB2, mB3, hB2, hB3);                       \
                FMA16(jB + 16, endB, mB2, mB3, hB2, hB3, AB);                         \
            }                                                                         \
            jB += 32;                                                                 \
        }                                                                             \
        _Pragma("unroll")                                                             \
        for (int i_ = 0; i_ < 8; ++i_) {                                              \
            AA[i_] += __shfl_xor(AA[i_], 8);                                          \
            AA[i_] += __shfl_xor(AA[i_], 16);                                         \
            AA[i_] += __shfl_xor(AA[i_], 32);                                         \
            AB[i_] += __shfl_xor(AB[i_], 8);                                          \
            AB[i_] += __shfl_xor(AB[i_], 16);                                         \
            AB[i_] += __shfl_xor(AB[i_], 32);                                         \
        }                                                                             \
    }

__global__ void spmm2r_kernel(const uint32* __restrict__ rowptr, const int2* __restrict__ pairs,
                              const char* __restrict__ hb, const uint4* __restrict__ prev,
                              uint4* __restrict__ out, float scale, int N) {
    int wid = blockIdx.x * 4 + (threadIdx.x >> 6);
    int nA = wid * 2;
    if (nA >= N) return;
    int lane = threadIdx.x & 63;
    int q = lane >> 3;
    int sub = lane & 7;
    int off = sub * 16;

    // prev values: q==0 lanes hold row A's, q==1 lanes hold row B's (issued before gather chain)
    int nq = nA + (q & 1);
    uint4 pv = make_uint4(0u, 0u, 0u, 0u);
    if (prev && q < 2 && nq < N) pv = prev[(size_t)nq * 8 + sub];

    float aA[8], aB[8];
    #pragma unroll
    for (int i = 0; i < 8; ++i) { aA[i] = 0.0f; aB[i] = 0.0f; }

    SPMM_BURST(nA, aA, aB);

    if (q < 2 && nq < N) {
        bool isB = (q == 1);
        float r[8];
        #pragma unroll
        for (int i = 0; i < 8; ++i) r[i] = scale * (isB ? aB[i] : aA[i]);
        if (prev) {
            r[0] -= __uint_as_float(pv.x << 16);
            r[1] -= __uint_as_float(pv.x & 0xFFFF0000u);
            r[2] -= __uint_as_float(pv.y << 16);
            r[3] -= __uint_as_float(pv.y & 0xFFFF0000u);
            r[4] -= __uint_as_float(pv.z << 16);
            r[5] -= __uint_as_float(pv.z & 0xFFFF0000u);
            r[6] -= __uint_as_float(pv.w << 16);
            r[7] -= __uint_as_float(pv.w & 0xFFFF0000u);
        }
        uint4 pack;
        pack.x = f2bf_u(r[0]) | (f2bf_u(r[1]) << 16);
        pack.y = f2bf_u(r[2]) | (f2bf_u(r[3]) << 16);
        pack.z = f2bf_u(r[4]) | (f2bf_u(r[5]) << 16);
        pack.w = f2bf_u(r[6]) | (f2bf_u(r[7]) << 16);
        out[(size_t)nq * 8 + sub] = pack;
    }
}

// ---------------- fused SpMM pass 3 + MFMA GEMM ----------------
// Block = 4 waves x 64 rows. Each wave computes T3 = 2*spmm(T2) - T1 for ITS 16 rows via 8
// sequential 2-row bursts, writing bf16 fragments into an LDS tile laid out exactly like the
// global row*8+quad layout. No barrier: each wave's MFMA reads only its own rows. Epilogue:
// out = bias + xb@W0 + T1@W1 + T2@W2 + T3(LDS)@W3 — T3 never touches HBM (saves 25.6MB RW
// + one dispatch; gemm's reads/MFMA hide under the gather latency).
__global__ void spmm_gemm_kernel(const uint32* __restrict__ rowptr, const int2* __restrict__ pairs,
                                 const char* __restrict__ hb /*T2*/, const uint4* __restrict__ prev /*T1*/,
                                 const uint4* __restrict__ h0, const uint4* __restrict__ h1,
                                 const uint4* __restrict__ h2,
                                 const uint4* __restrict__ Wf, const float* __restrict__ bias,
                                 float* __restrict__ out, int N) {
    __shared__ uint4 lds3[64][8];
    int tid = threadIdx.x;
    int wave = tid >> 6;
    int lane = tid & 63;
    int q = lane >> 3;
    int sub = lane & 7;
    int off = sub * 16;
    int wrow = blockIdx.x * 64 + wave * 16;      // this wave's 16 rows

    #pragma unroll 1
    for (int t = 0; t < 8; ++t) {
        int nA = wrow + 2 * t;
        int ls = wave * 16 + 2 * t;
        int nq = nA + (q & 1);
        if (nA >= N) {
            if (q < 2) lds3[ls + (q & 1)][sub] = make_uint4(0u, 0u, 0u, 0u);
            continue;
        }
        uint4 pv = make_uint4(0u, 0u, 0u, 0u);
        if (q < 2 && nq < N) pv = prev[(size_t)nq * 8 + sub];

        float aA[8], aB[8];
        #pragma unroll
        for (int i = 0; i < 8; ++i) { aA[i] = 0.0f; aB[i] = 0.0f; }

        SPMM_BURST(nA, aA, aB);

        if (q < 2) {
            uint4 pack = make_uint4(0u, 0u, 0u, 0u);
            if (nq < N) {
                bool isB = (q == 1);
                float r[8];
                #pragma unroll
                for (int i = 0; i < 8; ++i) r[i] = 2.0f * (isB ? aB[i] : aA[i]);
                r[0] -= __uint_as_float(pv.x << 16);
                r[1] -= __uint_as_float(pv.x & 0xFFFF0000u);
                r[2] -= __uint_as_float(pv.y << 16);
                r[3] -= __uint_as_float(pv.y & 0xFFFF0000u);
                r[4] -= __uint_as_float(pv.z << 16);
                r[5] -= __uint_as_float(pv.z & 0xFFFF0000u);
                r[6] -= __uint_as_float(pv.w << 16);
                r[7] -= __uint_as_float(pv.w & 0xFFFF0000u);
                pack.x = f2bf_u(r[0]) | (f2bf_u(r[1]) << 16);
                pack.y = f2bf_u(r[2]) | (f2bf_u(r[3]) << 16);
                pack.z = f2bf_u(r[4]) | (f2bf_u(r[5]) << 16);
                pack.w = f2bf_u(r[6]) | (f2bf_u(r[7]) << 16);
            }
            lds3[ls + (q & 1)][sub] = pack;
        }
    }

    // ---- MFMA epilogue (per-wave; reads only this wave's LDS rows) ----
    int quad = lane >> 4;
    int lo = lane & 15;
    int mrow = wrow + lo;
    int mclamp = min(mrow, N - 1);

    f32x4 acc[4] = {{0.f,0.f,0.f,0.f},{0.f,0.f,0.f,0.f},{0.f,0.f,0.f,0.f},{0.f,0.f,0.f,0.f}};
    const uint4* hs[3] = { h0, h1, h2 };
    #pragma unroll
    for (int w = 0; w < 3; ++w) {
        union { uint4 u; bf16x8 v; } a0, a1;
        a0.u = hs[w][(size_t)mclamp * 8 + quad];       // kh = 0
        a1.u = hs[w][(size_t)mclamp * 8 + 4 + quad];   // kh = 1
        #pragma unroll
        for (int t = 0; t < 4; ++t) {
            union { uint4 u; bf16x8 v; } b0, b1;
            b0.u = Wf[(w * 8 + t * 2 + 0) * 64 + lane];
            b1.u = Wf[(w * 8 + t * 2 + 1) * 64 + lane];
            acc[t] = __builtin_amdgcn_mfma_f32_16x16x32_bf16(a0.v, b0.v, acc[t], 0, 0, 0);
            acc[t] = __builtin_amdgcn_mfma_f32_16x16x32_bf16(a1.v, b1.v, acc[t], 0, 0, 0);
        }
    }
    {   // w = 3: T3 fragments from LDS
        union { uint4 u; bf16x8 v; } a0, a1;
        a0.u = lds3[wave * 16 + lo][quad];
        a1.u = lds3[wave * 16 + lo][4 + quad];
        #pragma unroll
        for (int t = 0; t < 4; ++t) {
            union { uint4 u; bf16x8 v; } b0, b1;
            b0.u = Wf[(3 * 8 + t * 2 + 0) * 64 + lane];
            b1.u = Wf[(3 * 8 + t * 2 + 1) * 64 + lane];
            acc[t] = __builtin_amdgcn_mfma_f32_16x16x32_bf16(a0.v, b0.v, acc[t], 0, 0, 0);
            acc[t] = __builtin_amdgcn_mfma_f32_16x16x32_bf16(a1.v, b1.v, acc[t], 0, 0, 0);
        }
    }
    #pragma unroll
    for (int t = 0; t < 4; ++t) {
        int col = t * 16 + lo;
        float bv = bias[col];
        #pragma unroll
        for (int r = 0; r < 4; ++r) {
            int rowi = wrow + quad * 4 + r;
            if (rowi < N) out[(size_t)rowi * 64 + col] = acc[t][r] + bv;
        }
    }
}

extern "C" void kernel_launch(void* const* d_in, const int* in_sizes, int n_in,
                              void* d_out, int out_size, void* d_ws, size_t ws_size,
                              hipStream_t stream) {
    const float* x    = (const float*)d_in[0];
    const int*   ei   = (const int*)d_in[1];
    const float* attr = (const float*)d_in[2];
    const float* W    = (const float*)d_in[3];   // [4,64,64]
    const float* bias = (const float*)d_in[4];   // [64]
    float* out = (float*)d_out;

    const int N = in_sizes[0] / D;
    const int E = in_sizes[1] / 2;
    const int* row = ei;        // edge_index[0]
    const int* col = ei + E;    // edge_index[1]
    const int NB = (N + NODES_PER_BKT - 1) >> NBSHIFT;

    // workspace layout — 16B-aligned arrays first
    char* p = (char*)d_ws;
    int2*     pairs   = (int2*)p;                p += (size_t)E * 8;
    uint2*    xb      = (uint2*)p;               p += (size_t)N * D * 2;
    uint2*    T1      = (uint2*)p;               p += (size_t)N * D * 2;
    uint2*    T2      = (uint2*)p;               p += (size_t)N * D * 2;
    int2*     binned  = (int2*)p;                p += (size_t)N * D * 2;   // scratch (old T3 slot)
    uint4*    Wf      = (uint4*)p;               p += 2048 * 16;
    uint32*   rowptr  = (uint32*)p;              p += (size_t)(N + 1) * 4;
    uint32*   bcount  = (uint32*)p;              p += 256 * 4;   // memset'd
    uint32*   gcursor = (uint32*)p;              p += 256 * 4;   // memset'd (zero-based cursor)
    float*    dinv    = (float*)p;               /* p += N*4 */

    const int gSp = (N + 7) / 8;                 // 2 rows/wave, 4 waves/block
    const int gFg = (N + 63) / 64;               // fused spmm3+gemm: 64 rows/block
    const int gTile = (E + TA - 1) / TA;

    // ---- build CSR (bucketed counting sort) + dinv + bf16 x/W ----
    hipMemsetAsync(bcount, 0, 512 * 4, stream);                        // bcount + gcursor
    pre_kernel<<<CVT_BLOCKS + 8 + gTile, BLK, 0, stream>>>(x, xb, N * D / 4, W, Wf,
                                                           row, bcount, E);
    binA_kernel<<<gTile, 256, 0, stream>>>(row, col, attr, bcount, gcursor, binned, E);
    binBdeg_kernel<<<NB, 256, 0, stream>>>(binned, bcount, rowptr, dinv, N, E);
    binBsort_kernel<<<NB, 256, 0, stream>>>(binned, bcount, rowptr, dinv, pairs, N);

    // ---- Chebyshev recurrence (bf16 storage, fp32 math) ----
    // T1 = spmm(xb)
    spmm2r_kernel<<<gSp, BLK, 0, stream>>>(rowptr, pairs, (const char*)xb, nullptr, (uint4*)T1, 1.0f, N);
    // T2 = 2*spmm(T1) - x
    spmm2r_kernel<<<gSp, BLK, 0, stream>>>(rowptr, pairs, (const char*)T1, (const uint4*)xb, (uint4*)T2, 2.0f, N);
    // fused: T3 = 2*spmm(T2) - T1 (LDS only) ; out = bias + xb@W0 + T1@W1 + T2@W2 + T3@W3
    spmm_gemm_kernel<<<gFg, BLK, 0, stream>>>(rowptr, pairs, (const char*)T2, (const uint4*)T1,
                                              (const uint4*)xb, (const uint4*)T1, (const uint4*)T2,
                                              Wf, bias, out, N);
}

// Round 10
// 284.567 us; speedup vs baseline: 1.0355x; 1.0355x over previous
//
#include <hip/hip_runtime.h>

#define D 64
#define BLK 256

#define NBSHIFT 9
#define NODES_PER_BKT 512              // bucket = row >> 9; NB <= 256 for N <= 131072
#define TA 4096                        // edges per binA tile
#define CVT_BLOCKS 512                 // grid-strided cvt

typedef unsigned int uint32;
typedef __attribute__((ext_vector_type(8))) short bf16x8;
typedef __attribute__((ext_vector_type(4))) float f32x4;

// ---- bf16 helpers (RTNE) ----
__device__ inline uint32 f2bf_u(float f) {
    uint32 u = __float_as_uint(f);
    u += 0x7FFFu + ((u >> 16) & 1u);
    return u >> 16;
}

// ---------------- fused pre-pass: cvt (grid-stride x->bf16) + wf (W repack) + hist ----------------
__global__ void pre_kernel(const float* __restrict__ x, uint2* __restrict__ xb, int n4,
                           const float* __restrict__ W, uint4* __restrict__ Wf,
                           const int* __restrict__ row, uint32* __restrict__ bcount, int E) {
    int bid = blockIdx.x;
    if (bid < CVT_BLOCKS) {
        int stride = CVT_BLOCKS * BLK;
        for (int i = bid * BLK + threadIdx.x; i < n4; i += stride) {
            float4 v = ((const float4*)x)[i];
            uint2 pack;
            pack.x = f2bf_u(v.x) | (f2bf_u(v.y) << 16);
            pack.y = f2bf_u(v.z) | (f2bf_u(v.w) << 16);
            xb[i] = pack;
        }
        return;
    }
    if (bid < CVT_BLOCKS + 8) {
        int tid = (bid - CVT_BLOCKS) * 256 + threadIdx.x;   // 0..2047
        int l = tid & 63;
        int g = tid >> 6;       // 0..31
        int kh = g & 1;
        int t = (g >> 1) & 3;
        int w = g >> 3;
        int n = t * 16 + (l & 15);
        int kbase = kh * 32 + (l >> 4) * 8;
        uint32 pk[4];
        #pragma unroll
        for (int i = 0; i < 4; ++i) {
            uint32 b0 = f2bf_u(W[(size_t)w * 4096 + (size_t)(kbase + 2 * i) * 64 + n]);
            uint32 b1 = f2bf_u(W[(size_t)w * 4096 + (size_t)(kbase + 2 * i + 1) * 64 + n]);
            pk[i] = b0 | (b1 << 16);
        }
        Wf[tid] = make_uint4(pk[0], pk[1], pk[2], pk[3]);
        return;
    }
    // hist
    __shared__ uint32 h[256];
    int tid = threadIdx.x;
    h[tid] = 0;
    __syncthreads();
    int base = (bid - CVT_BLOCKS - 8) * TA;
    int end = min(base + TA, E);
    for (int e = base + tid; e < end; e += 256)
        atomicAdd(&h[(uint32)row[e] >> NBSHIFT], 1u);
    __syncthreads();
    if (h[tid]) atomicAdd(&bcount[tid], h[tid]);
}

// ---------------- pass A: bin (rowlocal<<17|col, attr) by bucket ----------------
// Bucket-base scan of bcount recomputed locally (R5-proven); gcursor is a zero-based cursor.
__global__ void binA_kernel(const int* __restrict__ row, const int* __restrict__ col,
                            const float* __restrict__ attr, const uint32* __restrict__ bcount,
                            uint32* __restrict__ gcursor, int2* __restrict__ binned, int E) {
    __shared__ uint32 hist[256], baseg[256], lstart[256], lcur[256];
    __shared__ int2 stage[TA];
    __shared__ unsigned char sbkt[TA];
    int tid = threadIdx.x;
    int tile = blockIdx.x * TA;
    hist[tid] = 0;
    __syncthreads();

    uint32 px[16], py[16], bk[16];
    #pragma unroll
    for (int k = 0; k < 16; ++k) {
        int e = tile + k * 256 + tid;
        bk[k] = 0xFFFFFFFFu;
        if (e < E) {
            int r = row[e], c = col[e];
            uint32 b = (uint32)r >> NBSHIFT;
            bk[k] = b;
            px[k] = ((uint32)(r & (NODES_PER_BKT - 1)) << 17) | (uint32)c;
            py[k] = __float_as_uint(attr[e]);
            atomicAdd(&hist[b], 1u);
        }
    }
    __syncthreads();
    // local scan of bcount -> global bucket bases
    uint32 bc = bcount[tid];
    lcur[tid] = bc;
    __syncthreads();
    for (int off = 1; off < 256; off <<= 1) {
        uint32 t = (tid >= off) ? lcur[tid - off] : 0u;
        __syncthreads();
        lcur[tid] += t;
        __syncthreads();
    }
    uint32 gexcl = lcur[tid] - bc;
    if (hist[tid] > 0) baseg[tid] = gexcl + atomicAdd(&gcursor[tid], hist[tid]);
    __syncthreads();
    // local scan of this tile's histogram
    lcur[tid] = hist[tid];
    __syncthreads();
    for (int off = 1; off < 256; off <<= 1) {
        uint32 t = (tid >= off) ? lcur[tid - off] : 0u;
        __syncthreads();
        lcur[tid] += t;
        __syncthreads();
    }
    lstart[tid] = lcur[tid] - hist[tid];
    lcur[tid] = lstart[tid];
    __syncthreads();
    #pragma unroll
    for (int k = 0; k < 16; ++k) {
        if (bk[k] != 0xFFFFFFFFu) {
            uint32 pos = atomicAdd(&lcur[bk[k]], 1u);
            stage[pos] = make_int2((int)px[k], (int)py[k]);
            sbkt[pos] = (unsigned char)bk[k];
        }
    }
    __syncthreads();
    int cnt = min(TA, E - tile);
    for (int i = tid; i < cnt; i += 256) {
        uint32 b = sbkt[i];
        uint32 dst = baseg[b] + (uint32)i - lstart[b];
        binned[dst] = stage[i];
    }
}

// ---------------- pass B1: per-bucket degree count in LDS -> rowptr + dinv ----------------
// (Separate B1/B2 kernels deliberately: kernel-boundary L2 writeback beats R6's grid.sync fusion.)
__global__ void binBdeg_kernel(const int2* __restrict__ binned, const uint32* __restrict__ bcount,
                               uint32* __restrict__ rowptr, float* __restrict__ dinv,
                               int N, int E) {
    __shared__ uint32 cnt[NODES_PER_BKT];
    __shared__ uint32 ps[256];
    int b = blockIdx.x;
    int tid = threadIdx.x;
    cnt[tid] = 0;
    cnt[tid + 256] = 0;
    // local inclusive scan of bcount -> bucket [start,end)
    uint32 bc = bcount[tid];
    ps[tid] = bc;
    __syncthreads();
    for (int off = 1; off < 256; off <<= 1) {
        uint32 t = (tid >= off) ? ps[tid - off] : 0u;
        __syncthreads();
        ps[tid] += t;
        __syncthreads();
    }
    uint32 incl_b = ps[b];
    uint32 bc_b = bcount[b];
    uint32 start = incl_b - bc_b, end = incl_b;
    __syncthreads();                      // done with ps as bucket scan
    for (uint32 i = start + tid; i < end; i += 256)
        atomicAdd(&cnt[(uint32)binned[i].x >> 17], 1u);
    __syncthreads();
    uint32 c0 = cnt[2 * tid], c1 = cnt[2 * tid + 1];
    ps[tid] = c0 + c1;
    __syncthreads();
    for (int off = 1; off < 256; off <<= 1) {
        uint32 t = (tid >= off) ? ps[tid - off] : 0u;
        __syncthreads();
        ps[tid] += t;
        __syncthreads();
    }
    uint32 pexcl = ps[tid] - (c0 + c1);
    int base = b << NBSHIFT;
    int n0 = base + 2 * tid, n1 = n0 + 1;
    if (n0 < N) {
        rowptr[n0] = start + pexcl;
        dinv[n0] = c0 ? rsqrtf((float)c0) : 0.0f;
    }
    if (n1 < N) {
        rowptr[n1] = start + pexcl + c0;
        dinv[n1] = c1 ? rsqrtf((float)c1) : 0.0f;
    }
    if (b == (int)gridDim.x - 1 && tid == 0) rowptr[N] = (uint32)E;
}

// ---------------- pass B2: per-bucket sort + lap; pairs.x = col<<7 (byte offset) ----------------
__global__ void binBsort_kernel(const int2* __restrict__ binned, const uint32* __restrict__ bcount,
                                const uint32* __restrict__ rowptr, const float* __restrict__ dinv,
                                int2* __restrict__ pairs, int N) {
    __shared__ uint32 lcur[NODES_PER_BKT];
    __shared__ float ldin[NODES_PER_BKT];
    __shared__ uint32 ps[256];
    int b = blockIdx.x;
    int tid = threadIdx.x;
    int base = b << NBSHIFT;
    // local inclusive scan of bcount -> bucket [start,end)
    uint32 bc = bcount[tid];
    ps[tid] = bc;
    __syncthreads();
    for (int off = 1; off < 256; off <<= 1) {
        uint32 t = (tid >= off) ? ps[tid - off] : 0u;
        __syncthreads();
        ps[tid] += t;
        __syncthreads();
    }
    uint32 incl_b = ps[b];
    uint32 start = incl_b - bcount[b], end = incl_b;
    for (int t = tid; t < NODES_PER_BKT; t += 256) {
        int node = base + t;
        lcur[t] = (node < N) ? (rowptr[node] - start) : 0u;
        ldin[t] = (node < N) ? dinv[node] : 0.0f;
    }
    __syncthreads();
    for (uint32 i = start + tid; i < end; i += 256) {
        int2 rec = binned[i];
        uint32 x = (uint32)rec.x;
        uint32 rl = x >> 17;
        uint32 c = x & 0x1FFFFu;
        float lap = -ldin[rl] * __int_as_float(rec.y) * dinv[c];
        uint32 pos = atomicAdd(&lcur[rl], 1u);
        pairs[start + pos] = make_int2((int)(c << 7), __float_as_int(lap));
    }
}

// ---------------- CSR SpMM v7 (measured best; ~92-95% of random-line-fill roofline) ----------------
#define LOAD16(J, END, ESAFE, M0, M1, H0, H1)                          \
    {                                                                  \
        uint32 i0_ = (J) + q, i1_ = (J) + 8 + q;                       \
        uint32 c0_ = (i0_ < (END)) ? i0_ : (ESAFE);                    \
        uint32 c1_ = (i1_ < (END)) ? i1_ : (ESAFE);                    \
        M0 = pairs[c0_];                                               \
        M1 = pairs[c1_];                                               \
        H0 = *(const uint4*)(hb + (uint32)M0.x + off);                 \
        H1 = *(const uint4*)(hb + (uint32)M1.x + off);                 \
    }

#define FMA16(J, END, M0, M1, H0, H1, A)                               \
    {                                                                  \
        uint32 i0_ = (J) + q, i1_ = (J) + 8 + q;                       \
        float l0_ = (i0_ < (END)) ? __int_as_float(M0.y) : 0.0f;       \
        float l1_ = (i1_ < (END)) ? __int_as_float(M1.y) : 0.0f;       \
        A[0] += l0_ * __uint_as_float(H0.x << 16);                     \
        A[1] += l0_ * __uint_as_float(H0.x & 0xFFFF0000u);             \
        A[2] += l0_ * __uint_as_float(H0.y << 16);                     \
        A[3] += l0_ * __uint_as_float(H0.y & 0xFFFF0000u);             \
        A[4] += l0_ * __uint_as_float(H0.z << 16);                     \
        A[5] += l0_ * __uint_as_float(H0.z & 0xFFFF0000u);             \
        A[6] += l0_ * __uint_as_float(H0.w << 16);                     \
        A[7] += l0_ * __uint_as_float(H0.w & 0xFFFF0000u);             \
        A[0] += l1_ * __uint_as_float(H1.x << 16);                     \
        A[1] += l1_ * __uint_as_float(H1.x & 0xFFFF0000u);             \
        A[2] += l1_ * __uint_as_float(H1.y << 16);                     \
        A[3] += l1_ * __uint_as_float(H1.y & 0xFFFF0000u);             \
        A[4] += l1_ * __uint_as_float(H1.z << 16);                     \
        A[5] += l1_ * __uint_as_float(H1.z & 0xFFFF0000u);             \
        A[6] += l1_ * __uint_as_float(H1.w << 16);                     \
        A[7] += l1_ * __uint_as_float(H1.w & 0xFFFF0000u);             \
    }

__global__ void spmm2r_kernel(const uint32* __restrict__ rowptr, const int2* __restrict__ pairs,
                              const char* __restrict__ hb, const uint4* __restrict__ prev,
                              uint4* __restrict__ out, float scale, int N) {
    int wid = blockIdx.x * 4 + (threadIdx.x >> 6);
    int nA = wid * 2;
    if (nA >= N) return;
    int lane = threadIdx.x & 63;
    int q = lane >> 3;
    int sub = lane & 7;
    int off = sub * 16;
    bool hasB = (nA + 1 < N);

    uint2 rpA = *(const uint2*)(rowptr + nA);              // nA even -> 8B aligned
    uint32 eBr = hasB ? rowptr[nA + 2] : rpA.y;
    uint32 jA   = __builtin_amdgcn_readfirstlane(rpA.x);   // SGPR bounds -> uniform branches
    uint32 endA = __builtin_amdgcn_readfirstlane(rpA.y);
    uint32 jB   = endA;
    uint32 endB = __builtin_amdgcn_readfirstlane(eBr);
    uint32 esA = (endA > jA) ? endA - 1 : 0u;              // safe clamp target (pairs[0] valid)
    uint32 esB = (endB > jB) ? endB - 1 : 0u;

    // prev values: q==0 lanes hold row A's, q==1 lanes hold row B's (issued before gather chain)
    int nq = nA + (q & 1);
    uint4 pv = make_uint4(0u, 0u, 0u, 0u);
    if (prev && q < 2 && nq < N) pv = prev[(size_t)nq * 8 + sub];

    float aA[8], aB[8];
    #pragma unroll
    for (int i = 0; i < 8; ++i) { aA[i] = 0.0f; aB[i] = 0.0f; }

    int2 mA0, mA1, mA2, mA3, mB0, mB1, mB2, mB3;
    uint4 hA0, hA1, hA2, hA3, hB0, hB1, hB2, hB3;

    bool dA = (jA + 16 < endA);    // scalar: row A needs upper half
    bool dB = (jB + 16 < endB);

    LOAD16(jA, endA, esA, mA0, mA1, hA0, hA1);
    LOAD16(jB, endB, esB, mB0, mB1, hB0, hB1);
    if (dA) LOAD16(jA + 16, endA, esA, mA2, mA3, hA2, hA3);
    if (dB) LOAD16(jB + 16, endB, esB, mB2, mB3, hB2, hB3);
    FMA16(jA, endA, mA0, mA1, hA0, hA1, aA);
    FMA16(jB, endB, mB0, mB1, hB0, hB1, aB);
    if (dA) FMA16(jA + 16, endA, mA2, mA3, hA2, hA3, aA);
    if (dB) FMA16(jB + 16, endB, mB2, mB3, hB2, hB3, aB);
    jA += 32;
    jB += 32;

    // rare tails (deg > 32; P ~ 3e-5 at Poisson-16) — scalar-uniform loops
    while (jA < endA) {
        LOAD16(jA, endA, esA, mA0, mA1, hA0, hA1);
        FMA16(jA, endA, mA0, mA1, hA0, hA1, aA);
        if (jA + 16 < endA) {
            LOAD16(jA + 16, endA, esA, mA2, mA3, hA2, hA3);
            FMA16(jA + 16, endA, mA2, mA3, hA2, hA3, aA);
        }
        jA += 32;
    }
    while (jB < endB) {
        LOAD16(jB, endB, esB, mB0, mB1, hB0, hB1);
        FMA16(jB, endB, mB0, mB1, hB0, hB1, aB);
        if (jB + 16 < endB) {
            LOAD16(jB + 16, endB, esB, mB2, mB3, hB2, hB3);
            FMA16(jB + 16, endB, mB2, mB3, hB2, hB3, aB);
        }
        jB += 32;
    }

    #pragma unroll
    for (int i = 0; i < 8; ++i) {
        aA[i] += __shfl_xor(aA[i], 8);
        aA[i] += __shfl_xor(aA[i], 16);
        aA[i] += __shfl_xor(aA[i], 32);
        aB[i] += __shfl_xor(aB[i], 8);
        aB[i] += __shfl_xor(aB[i], 16);
        aB[i] += __shfl_xor(aB[i], 32);
    }

    if (q < 2 && nq < N) {
        bool isB = (q == 1);
        float r[8];
        #pragma unroll
        for (int i = 0; i < 8; ++i) r[i] = scale * (isB ? aB[i] : aA[i]);
        if (prev) {
            r[0] -= __uint_as_float(pv.x << 16);
            r[1] -= __uint_as_float(pv.x & 0xFFFF0000u);
            r[2] -= __uint_as_float(pv.y << 16);
            r[3] -= __uint_as_float(pv.y & 0xFFFF0000u);
            r[4] -= __uint_as_float(pv.z << 16);
            r[5] -= __uint_as_float(pv.z & 0xFFFF0000u);
            r[6] -= __uint_as_float(pv.w << 16);
            r[7] -= __uint_as_float(pv.w & 0xFFFF0000u);
        }
        uint4 pack;
        pack.x = f2bf_u(r[0]) | (f2bf_u(r[1]) << 16);
        pack.y = f2bf_u(r[2]) | (f2bf_u(r[3]) << 16);
        pack.z = f2bf_u(r[4]) | (f2bf_u(r[5]) << 16);
        pack.w = f2bf_u(r[6]) | (f2bf_u(r[7]) << 16);
        out[(size_t)nq * 8 + sub] = pack;
    }
}

// ---------------- fused MFMA GEMM: out = bias + x@W0 + T1@W1 + T2@W2 + T3@W3 ----------------
__global__ void gemm_mfma(const uint4* __restrict__ h0, const uint4* __restrict__ h1,
                          const uint4* __restrict__ h2, const uint4* __restrict__ h3,
                          const uint4* __restrict__ Wf, const float* __restrict__ bias,
                          float* __restrict__ out, int N) {
    int tid = threadIdx.x;
    int wave = tid >> 6;
    int lane = tid & 63;
    int quad = lane >> 4;
    int lo = lane & 15;
    int m0 = blockIdx.x * 64 + wave * 16;
    int mrow = m0 + lo;
    int mclamp = min(mrow, N - 1);

    f32x4 acc[4] = {{0.f,0.f,0.f,0.f},{0.f,0.f,0.f,0.f},{0.f,0.f,0.f,0.f},{0.f,0.f,0.f,0.f}};
    const uint4* hs[4] = { h0, h1, h2, h3 };
    #pragma unroll
    for (int w = 0; w < 4; ++w) {
        union { uint4 u; bf16x8 v; } a0, a1;
        a0.u = hs[w][(size_t)mclamp * 8 + quad];       // kh = 0
        a1.u = hs[w][(size_t)mclamp * 8 + 4 + quad];   // kh = 1
        #pragma unroll
        for (int t = 0; t < 4; ++t) {
            union { uint4 u; bf16x8 v; } b0, b1;
            b0.u = Wf[(w * 8 + t * 2 + 0) * 64 + lane];
            b1.u = Wf[(w * 8 + t * 2 + 1) * 64 + lane];
            acc[t] = __builtin_amdgcn_mfma_f32_16x16x32_bf16(a0.v, b0.v, acc[t], 0, 0, 0);
            acc[t] = __builtin_amdgcn_mfma_f32_16x16x32_bf16(a1.v, b1.v, acc[t], 0, 0, 0);
        }
    }
    #pragma unroll
    for (int t = 0; t < 4; ++t) {
        int col = t * 16 + lo;
        float bv = bias[col];
        #pragma unroll
        for (int r = 0; r < 4; ++r) {
            int rowi = m0 + quad * 4 + r;
            if (rowi < N) out[(size_t)rowi * 64 + col] = acc[t][r] + bv;
        }
    }
}

extern "C" void kernel_launch(void* const* d_in, const int* in_sizes, int n_in,
                              void* d_out, int out_size, void* d_ws, size_t ws_size,
                              hipStream_t stream) {
    const float* x    = (const float*)d_in[0];
    const int*   ei   = (const int*)d_in[1];
    const float* attr = (const float*)d_in[2];
    const float* W    = (const float*)d_in[3];   // [4,64,64]
    const float* bias = (const float*)d_in[4];   // [64]
    float* out = (float*)d_out;

    const int N = in_sizes[0] / D;
    const int E = in_sizes[1] / 2;
    const int* row = ei;        // edge_index[0]
    const int* col = ei + E;    // edge_index[1]
    const int NB = (N + NODES_PER_BKT - 1) >> NBSHIFT;

    // workspace layout — 16B-aligned arrays first
    char* p = (char*)d_ws;
    int2*     pairs   = (int2*)p;                p += (size_t)E * 8;
    uint2*    xb      = (uint2*)p;               p += (size_t)N * D * 2;
    uint2*    T1      = (uint2*)p;               p += (size_t)N * D * 2;
    uint2*    T2      = (uint2*)p;               p += (size_t)N * D * 2;
    uint2*    T3      = (uint2*)p;               p += (size_t)N * D * 2;
    uint4*    Wf      = (uint4*)p;               p += 2048 * 16;
    uint32*   rowptr  = (uint32*)p;              p += (size_t)(N + 1) * 4;
    uint32*   bcount  = (uint32*)p;              p += 256 * 4;   // memset'd
    uint32*   gcursor = (uint32*)p;              p += 256 * 4;   // memset'd (zero-based cursor)
    float*    dinv    = (float*)p;               /* p += N*4 */
    // binned aliases T3: consumed by binB* before 3rd spmm writes T3
    int2*     binned  = (int2*)T3;

    const int gSp = (N + 7) / 8;                 // 2 rows/wave, 4 waves/block
    const int gGm = (N + 63) / 64;
    const int gTile = (E + TA - 1) / TA;

    // ---- build CSR (bucketed counting sort) + dinv + bf16 x/W ----
    hipMemsetAsync(bcount, 0, 512 * 4, stream);                        // bcount + gcursor
    pre_kernel<<<CVT_BLOCKS + 8 + gTile, BLK, 0, stream>>>(x, xb, N * D / 4, W, Wf,
                                                           row, bcount, E);
    binA_kernel<<<gTile, 256, 0, stream>>>(row, col, attr, bcount, gcursor, binned, E);
    binBdeg_kernel<<<NB, 256, 0, stream>>>(binned, bcount, rowptr, dinv, N, E);
    binBsort_kernel<<<NB, 256, 0, stream>>>(binned, bcount, rowptr, dinv, pairs, N);

    // ---- Chebyshev recurrence (bf16 storage, fp32 math) ----
    // T1 = spmm(xb)
    spmm2r_kernel<<<gSp, BLK, 0, stream>>>(rowptr, pairs, (const char*)xb, nullptr, (uint4*)T1, 1.0f, N);
    // T2 = 2*spmm(T1) - x
    spmm2r_kernel<<<gSp, BLK, 0, stream>>>(rowptr, pairs, (const char*)T1, (const uint4*)xb, (uint4*)T2, 2.0f, N);
    // T3 = 2*spmm(T2) - T1   (binned already consumed)
    spmm2r_kernel<<<gSp, BLK, 0, stream>>>(rowptr, pairs, (const char*)T2, (const uint4*)T1, (uint4*)T3, 2.0f, N);
    // out = bias + x@W0 + T1@W1 + T2@W2 + T3@W3  (single MFMA GEMM, K=4x64)
    gemm_mfma<<<gGm, BLK, 0, stream>>>((const uint4*)xb, (const uint4*)T1, (const uint4*)T2,
                                       (const uint4*)T3, Wf, bias, out, N);
}